// Round 9
// baseline (1396.201 us; speedup 1.0000x reference)
//
#include <hip/hip_runtime.h>

typedef __attribute__((ext_vector_type(8))) short short8_t;
typedef __attribute__((ext_vector_type(16))) float f32x16;

#define NROWS_TOTAL 524288
#define MROWS 64
#define HSTRIDE 536   // 268 dw == 12 mod 32 -> b128 A-reads tile all 8 bank-quads (optimal 8-cyc service)
#define NTHREADS 512
#define OSTRIDE 108   // f32 out-staging stride

#define HBUF_USHORT (MROWS * HSTRIDE)        // 34,304 ushort = 68,608 B
#define LDS_TOTAL_USHORT (HBUF_USHORT + 2 * 16384)   // + 2 x 32KB B-stage = 134,144 B

__device__ __forceinline__ unsigned short f32_to_bf16(float f) {
    union { float f; unsigned int u; } v; v.f = f;
    unsigned int r = v.u + 0x7FFFu + ((v.u >> 16) & 1u);
    return (unsigned short)(r >> 16);
}

// ---------------------------------------------------------------------------
// Workspace layout: per-layer sequence of K-chunk PANELS, each panel holding
// B^T for one K=32 slice, XOR-swizzled so LDS reads are bank-conflict-free
// while global_load_lds writes stay linear (pre-swizzled-source pattern).
//   element (n, kk): kk = kh*16 + lh*8 + i  (kh,lh in {0,1}, i in 0..7)
//   bf16 off within panel = (((n<<5) + (kh<<4) + (lh<<3)) ^ ((n&7)<<3)) + i
// L1: 4 panels x 16384 bf16 @ 0       (K 105->128, N=512)
// L2: 16 panels x 16384     @ 65536
// L3: 16 panels x 16384     @ 327680
// L4: 16 panels x 4096      @ 589824  (N 100->128, K=512)
// ---------------------------------------------------------------------------
__global__ void conv_weights(const float* __restrict__ W1, const float* __restrict__ W2,
                             const float* __restrict__ W3, const float* __restrict__ W4,
                             unsigned short* __restrict__ ws) {
    int t = blockIdx.x * 256 + threadIdx.x;
    float v; int n, k, base;
    if (t < 65536)       { n = t & 511;                 k = t >> 9;          v = (k < 105) ? W1[k * 512 + n] : 0.f; base = 0      + (k >> 5) * 16384; }
    else if (t < 327680) { int u = t - 65536;  n = u & 511; k = u >> 9;      v = W2[k * 512 + n];                   base = 65536  + (k >> 5) * 16384; }
    else if (t < 589824) { int u = t - 327680; n = u & 511; k = u >> 9;      v = W3[k * 512 + n];                   base = 327680 + (k >> 5) * 16384; }
    else                 { int u = t - 589824; n = u & 127; k = u >> 7;      v = (n < 100) ? W4[k * 100 + n] : 0.f; base = 589824 + (k >> 5) * 4096;  }
    int kk = k & 31;
    int kh = kk >> 4, lh = (kk >> 3) & 1, i = kk & 7;
    int off = (((n << 5) + (kh << 4) + (lh << 3)) ^ ((n & 7) << 3)) + i;
    ws[base + off] = f32_to_bf16(v);
}

__device__ __forceinline__ int clamp_bin(float sc) {
    int b = (int)floorf(sc);
    return b < 0 ? 0 : (b > 15 ? 15 : b);
}

// async global->LDS, 16B per lane; LDS dest is wave-uniform base (+lane*16 by HW)
__device__ __forceinline__ void gl2lds16(const void* g, void* l) {
    __builtin_amdgcn_global_load_lds(
        (__attribute__((address_space(1))) void*)g,
        (__attribute__((address_space(3))) void*)l, 16, 0, 0);
}

// stage CALLS*8KB: 512 threads x 16B x CALLS
template<int CALLS>
__device__ __forceinline__ void stageN(char* dst, const char* src, int tid) {
    #pragma unroll
    for (int c = 0; c < CALLS; ++c)
        gl2lds16(src + c * 8192 + tid * 16, dst + c * 8192 + (tid >> 6) * 1024);
}

__device__ __forceinline__ void wait_vmcnt(int n) {   // folds to constant after unroll
    if (n == 0)      asm volatile("s_waitcnt vmcnt(0)" ::: "memory");
    else if (n == 1) asm volatile("s_waitcnt vmcnt(1)" ::: "memory");
    else             asm volatile("s_waitcnt vmcnt(4)" ::: "memory");
}

// ---------------------------------------------------------------------------
// One MLP layer (L1-L3): 8 waves, wave = 64 rows x 64 cols (acc[2][2] 32x32).
// Per chunk (RACE-FIXED order, m201 invariant: vmcnt -> BARRIER -> reads):
//   vmcnt(gate) ; s_barrier        <- all waves' chunk-kc staging now visible
//   ds_read B(4xb128)+A(4xb128) ; lgkmcnt(0); sched_barrier
//   s_barrier                      <- all waves' reads of buf p drained
//   DMA-stage chunk kc+2 -> buf p (own or next layer panel)
//   setprio(1) 8x MFMA setprio(0)
// gate = #vmem ops issued after chunk-kc's stage (= previous iter's stage count).
// ---------------------------------------------------------------------------
template<int KDIM, int NEXT_CALLS, int PREV_GATE>
__device__ __forceinline__ void mlp_layer(unsigned short* hbuf, char* bst,
                                          const unsigned short* Wt, const unsigned short* Wnext,
                                          const float* __restrict__ bias, int tid) {
    constexpr int NK = KDIM / 32;
    const int lane = tid & 63, wave = tid >> 6;
    const int l31 = lane & 31, lh = lane >> 5;
    const int n0 = wave * 64;
    const char* wt_b = (const char*)Wt;
    const char* wn_b = (const char*)Wnext;

    f32x16 acc[2][2];
    #pragma unroll
    for (int nt = 0; nt < 2; ++nt) {
        float bv = bias[n0 + nt * 32 + l31];
        #pragma unroll
        for (int mt = 0; mt < 2; ++mt)
            #pragma unroll
            for (int r = 0; r < 16; ++r) acc[mt][nt][r] = bv;
    }

    const char* ab = (const char*)hbuf + l31 * (HSTRIDE * 2) + lh * 16;
    int boff[2][2];
    #pragma unroll
    for (int nt = 0; nt < 2; ++nt)
        #pragma unroll
        for (int kh = 0; kh < 2; ++kh) {
            int n = n0 + nt * 32 + l31;
            boff[nt][kh] = ((n << 6) + (kh << 5) + (lh << 4)) ^ ((l31 & 7) << 4);
        }

    #pragma unroll
    for (int kc = 0; kc < NK; ++kc) {
        int gate = (kc == 0) ? PREV_GATE
                 : ((kc + 1) < NK ? 4 : (((kc + 1 - NK) < 2 && NEXT_CALLS > 0) ? NEXT_CALLS : 0));
        wait_vmcnt(gate);
        __builtin_amdgcn_s_barrier();        // barrier #1: chunk-kc staging visible to all
        const char* bp = bst + (kc & 1) * 32768;
        short8_t b[2][2], a[2][2];
        #pragma unroll
        for (int nt = 0; nt < 2; ++nt)
            #pragma unroll
            for (int kh = 0; kh < 2; ++kh)
                b[nt][kh] = *(const short8_t*)(bp + boff[nt][kh]);
        #pragma unroll
        for (int mt = 0; mt < 2; ++mt)
            #pragma unroll
            for (int kh = 0; kh < 2; ++kh)
                a[mt][kh] = *(const short8_t*)(ab + mt * (32 * HSTRIDE * 2) + kc * 64 + kh * 32);
        asm volatile("s_waitcnt lgkmcnt(0)" ::: "memory");
        __builtin_amdgcn_sched_barrier(0);
        __builtin_amdgcn_s_barrier();        // barrier #2: all reads of buf p drained
        char* mybuf = bst + (kc & 1) * 32768;
        if (kc + 2 < NK)
            stageN<4>(mybuf, wt_b + (kc + 2) * 32768, tid);
        else if (NEXT_CALLS > 0 && (kc + 2 - NK) < 2)
            stageN<NEXT_CALLS>(mybuf, wn_b + (kc + 2 - NK) * (NEXT_CALLS * 8192), tid);
        __builtin_amdgcn_s_setprio(1);
        #pragma unroll
        for (int kh = 0; kh < 2; ++kh)
            #pragma unroll
            for (int mt = 0; mt < 2; ++mt)
                #pragma unroll
                for (int nt = 0; nt < 2; ++nt)
                    acc[mt][nt] = __builtin_amdgcn_mfma_f32_32x32x16_bf16(
                        a[mt][kh], b[nt][kh], acc[mt][nt], 0, 0, 0);
        __builtin_amdgcn_s_setprio(0);
    }

    // Epilogue: relu (bias folded), pair-pack cols via shfl_xor(1), b32 LDS writes.
    // Safe: all waves passed barrier#2 of kc=NK-1 AFTER draining their A-reads.
    // 32x32 C/D: col = lane&31, row = (reg&3)+8*(reg>>2)+4*(lane>>5) (m74/m101).
    const int odd = lane & 1;
    const int colw = n0 + odd * 32 + (l31 & ~1);
    #pragma unroll
    for (int mt = 0; mt < 2; ++mt) {
        #pragma unroll
        for (int reg = 0; reg < 16; ++reg) {
            float vA = fmaxf(acc[mt][0][reg], 0.f);
            float vB = fmaxf(acc[mt][1][reg], 0.f);
            float vm = odd ? vB : vA;
            float vs = odd ? vA : vB;
            float vr = __shfl_xor(vs, 1, 64);
            unsigned int ha = f32_to_bf16(vm);
            unsigned int hb = f32_to_bf16(vr);
            unsigned int packed = odd ? (hb | (ha << 16)) : (ha | (hb << 16));
            int row = mt * 32 + (reg & 3) + 8 * (reg >> 2) + 4 * lh;
            *(unsigned int*)(hbuf + row * HSTRIDE + colw) = packed;
        }
    }
    asm volatile("s_waitcnt lgkmcnt(0)" ::: "memory");
    __builtin_amdgcn_s_barrier();
}

__global__ void __launch_bounds__(NTHREADS, 2)
pivnet_fused(const float* __restrict__ x,
             const float* __restrict__ minv, const float* __restrict__ maxv,
             const float* __restrict__ pivots, const float* __restrict__ knnd,
             const float* __restrict__ qmean, const float* __restrict__ qstd,
             const float* __restrict__ kmean, const float* __restrict__ kstd,
             const unsigned short* __restrict__ wsw,
             const float* __restrict__ b1, const float* __restrict__ b2,
             const float* __restrict__ b3, const float* __restrict__ b4,
             float* __restrict__ out) {
    __shared__ unsigned short lds_all[LDS_TOTAL_USHORT];   // 134,144 B -> 1 block/CU
    unsigned short* hbuf = lds_all;
    char* bst = (char*)(lds_all + HBUF_USHORT);

    const int tid  = threadIdx.x;
    const int lane = tid & 63;
    const int row0 = blockIdx.x * MROWS;
    const char* wsb = (const char*)wsw;

    // prologue: DMA L1 panels 0,1 into the two stage buffers (overlaps feature phase)
    stageN<4>(bst, wsb, tid);
    stageN<4>(bst + 32768, wsb + 32768, tid);

    // ---------------- feature phase: 8 threads per row ----------------
    {
        const int r = tid >> 3;          // 0..63 local row
        const int p = tid & 7;           // col group [p*16, p*16+16)
        const float mn0 = minv[0], mn1 = minv[1], mn2 = minv[2], mn3 = minv[3];
        const float rg0 = maxv[0] - mn0, rg1 = maxv[1] - mn1, rg2 = maxv[2] - mn2, rg3 = maxv[3] - mn3;
        const float cd2 = (rg0 * rg0 + rg1 * rg1 + rg2 * rg2 + rg3 * rg3) * (1.0f / 256.0f);
        const float4 xr = ((const float4*)x)[row0 + r];
        const float xa0 = xr.x, xa1 = xr.y, xa2 = xr.z, xa3 = xr.w;
        int bidx;
        bidx = clamp_bin((xa0 - mn0) / rg0 * 16.f);
        bidx = bidx * 16 + clamp_bin((xa1 - mn1) / rg1 * 16.f);
        bidx = bidx * 16 + clamp_bin((xa2 - mn2) / rg2 * 16.f);
        bidx = bidx * 16 + clamp_bin((xa3 - mn3) / rg3 * 16.f);
        const float* kr = knnd + (size_t)bidx * 100;

        unsigned short vals[16];
        if (p == 0) {
            vals[0] = f32_to_bf16((xa0 - qmean[0]) / qstd[0]);
            vals[1] = f32_to_bf16((xa1 - qmean[1]) / qstd[1]);
            vals[2] = f32_to_bf16((xa2 - qmean[2]) / qstd[2]);
            vals[3] = f32_to_bf16((xa3 - qmean[3]) / qstd[3]);
            const float4 pv = ((const float4*)pivots)[bidx];
            float d0 = xa0 - pv.x, d1 = xa1 - pv.y, d2 = xa2 - pv.z, d3 = xa3 - pv.w;
            vals[4] = f32_to_bf16(sqrtf((d0 * d0 + d1 * d1 + d2 * d2 + d3 * d3) / cd2));
            #pragma unroll
            for (int j = 5; j < 16; ++j) {
                int k = j - 5;
                vals[j] = f32_to_bf16((kr[k] - kmean[k]) / kstd[k]);
            }
        } else {
            #pragma unroll
            for (int j = 0; j < 16; ++j) {
                int k = p * 16 + j - 5;
                float f = 0.f;
                if (k < 100) f = (kr[k] - kmean[k]) / kstd[k];
                vals[j] = f32_to_bf16(f);
            }
        }
        unsigned int pk[8];
        #pragma unroll
        for (int j = 0; j < 8; ++j)
            pk[j] = (unsigned int)vals[2 * j] | ((unsigned int)vals[2 * j + 1] << 16);
        uint4* d4 = (uint4*)(hbuf + r * HSTRIDE + p * 16);
        d4[0] = make_uint4(pk[0], pk[1], pk[2], pk[3]);
        d4[1] = make_uint4(pk[4], pk[5], pk[6], pk[7]);
    }
    asm volatile("s_waitcnt lgkmcnt(0)" ::: "memory");
    __builtin_amdgcn_s_barrier();

    mlp_layer<128, 4, 4>(hbuf, bst, wsw,          wsw + 65536,  b1, tid);
    mlp_layer<512, 4, 4>(hbuf, bst, wsw + 65536,  wsw + 327680, b2, tid);
    mlp_layer<512, 1, 4>(hbuf, bst, wsw + 327680, wsw + 589824, b3, tid);

    // ---------------- layer 4: [64][512] x [512][100->128], 8KB panels ----
    {
        const int l31 = lane & 31, lh = lane >> 5;
        const int wave = tid >> 6;
        const int nt4 = wave & 3, rowg = wave >> 2;
        const int col = nt4 * 32 + l31;
        const char* w4_b = (const char*)(wsw + 589824);
        f32x16 acc;
        {
            float bv = (col < 100) ? b4[col] : 0.f;
            #pragma unroll
            for (int r = 0; r < 16; ++r) acc[r] = bv;
        }
        const char* ab = (const char*)hbuf + (rowg * 32 + l31) * (HSTRIDE * 2) + lh * 16;
        int boff[2];
        #pragma unroll
        for (int kh = 0; kh < 2; ++kh)
            boff[kh] = ((col << 6) + (kh << 5) + (lh << 4)) ^ ((l31 & 7) << 4);

        #pragma unroll
        for (int kc = 0; kc < 16; ++kc) {
            int gate = (kc == 0) ? 1 : ((kc + 1) < 16 ? 1 : 0);
            wait_vmcnt(gate);
            __builtin_amdgcn_s_barrier();    // barrier #1: panel kc visible
            const char* bp = bst + (kc & 1) * 32768;
            short8_t b0 = *(const short8_t*)(bp + boff[0]);
            short8_t b1r = *(const short8_t*)(bp + boff[1]);
            short8_t a0 = *(const short8_t*)(ab + kc * 64);
            short8_t a1 = *(const short8_t*)(ab + kc * 64 + 32);
            asm volatile("s_waitcnt lgkmcnt(0)" ::: "memory");
            __builtin_amdgcn_sched_barrier(0);
            __builtin_amdgcn_s_barrier();    // barrier #2: reads drained
            if (kc + 2 < 16)
                stageN<1>(bst + (kc & 1) * 32768, w4_b + (kc + 2) * 8192, tid);
            __builtin_amdgcn_s_setprio(1);
            acc = __builtin_amdgcn_mfma_f32_32x32x16_bf16(a0, b0, acc, 0, 0, 0);
            acc = __builtin_amdgcn_mfma_f32_32x32x16_bf16(a1, b1r, acc, 0, 0, 0);
            __builtin_amdgcn_s_setprio(0);
        }

        // stage f32 results in hbuf (all hbuf reads done: kc=15 barrier#2 after all lgkm0)
        float* fstage = (float*)hbuf;
        if (col < 100) {
            #pragma unroll
            for (int reg = 0; reg < 16; ++reg) {
                int row = rowg * 32 + (reg & 3) + 8 * (reg >> 2) + 4 * lh;
                fstage[row * OSTRIDE + col] = acc[reg];
            }
        }
        asm volatile("s_waitcnt lgkmcnt(0)" ::: "memory");
        __builtin_amdgcn_s_barrier();

        // contiguous 64*100*4 = 25,600 B span -> float4-coalesced copy
        float* obase = out + (size_t)row0 * 100;
        #pragma unroll
        for (int k = 0; k < 4; ++k) {
            int j = tid + k * 512;            // float4 index 0..1599
            if (j < 1600) {
                int row = j / 25;
                int c4  = j - row * 25;
                float4 v = *(const float4*)(fstage + row * OSTRIDE + c4 * 4);
                *(float4*)(obase + 4 * j) = v;
            }
        }
    }
}

extern "C" void kernel_launch(void* const* d_in, const int* in_sizes, int n_in,
                              void* d_out, int out_size, void* d_ws, size_t ws_size,
                              hipStream_t stream) {
    const float* x    = (const float*)d_in[0];
    const float* minv = (const float*)d_in[1];
    const float* maxv = (const float*)d_in[2];
    const float* piv  = (const float*)d_in[3];
    const float* knnd = (const float*)d_in[4];
    const float* qm   = (const float*)d_in[5];
    const float* qs   = (const float*)d_in[6];
    const float* km   = (const float*)d_in[7];
    const float* ks   = (const float*)d_in[8];
    const float* W1   = (const float*)d_in[9];
    const float* b1   = (const float*)d_in[10];
    const float* W2   = (const float*)d_in[11];
    const float* b2   = (const float*)d_in[12];
    const float* W3   = (const float*)d_in[13];
    const float* b3   = (const float*)d_in[14];
    const float* W4   = (const float*)d_in[15];
    const float* b4   = (const float*)d_in[16];
    float* out = (float*)d_out;
    unsigned short* wsw = (unsigned short*)d_ws;   // needs 1,310,720 B

    conv_weights<<<2560, 256, 0, stream>>>(W1, W2, W3, W4, wsw);
    pivnet_fused<<<NROWS_TOTAL / MROWS, NTHREADS, 0, stream>>>(
        x, minv, maxv, piv, knnd, qm, qs, km, ks,
        wsw, b1, b2, b3, b4, out);
}